// Round 21
// baseline (154.216 us; speedup 1.0000x reference)
//
#include <hip/hip_runtime.h>
#include <hip/hip_fp16.h>

#define NN 100000   // nodes
#define NE 3200000  // edges
#define NF 128      // in features
#define NH 32       // hidden
#define NG 512      // graphs
#define NR 196      // coarse ranges = ceil(NN/512)
#define RSZ 512     // nodes per range (dst>>9, dst&511)
#define CAP 17408   // reserved words per range (mean 16327 + 8 sigma)
#define EPB 4096    // edges per block in coarse scatter
#define NBE 782     // ceil(NE/EPB)
#define PNB 782     // pool blocks (128 nodes each)
#define PRSZ 128
#define ZV4 16512   // int4 count of s|mx|cnt region (264192 B / 16)

typedef int   v4i __attribute__((ext_vector_type(4)));
typedef float v4f __attribute__((ext_vector_type(4)));

__device__ __forceinline__ __half2 shfl_xor_h2(__half2 v, int m) {
    int iv = *(int*)&v;
    int r = __shfl_xor(iv, m);
    return *(__half2*)&r;
}

// ---- C1: coarse scatter, capacity reservation, single-pass rank capture ----
__global__ __launch_bounds__(256) void k_cscatter(const int* __restrict__ src,
                                                  const int* __restrict__ dst,
                                                  int* __restrict__ ccur,
                                                  unsigned int* __restrict__ cbucket) {
    __shared__ int h[NR];
    __shared__ int basev[NR];
    for (int i = threadIdx.x; i < NR; i += 256) h[i] = 0;
    __syncthreads();
    int base = blockIdx.x * EPB;
    int lim = NE - base;
    int4 dv[4], sv[4];
    int rank[4][4];
    int valid[4];
#pragma unroll
    for (int k = 0; k < 4; ++k) {
        int idx = threadIdx.x + k * 256;
        valid[k] = (idx * 4 < lim);
        if (valid[k]) {
            dv[k] = ((const int4*)(dst + base))[idx];
            sv[k] = ((const int4*)(src + base))[idx];
            rank[k][0] = atomicAdd(&h[dv[k].x >> 9], 1);  // count pass IS rank pass
            rank[k][1] = atomicAdd(&h[dv[k].y >> 9], 1);
            rank[k][2] = atomicAdd(&h[dv[k].z >> 9], 1);
            rank[k][3] = atomicAdd(&h[dv[k].w >> 9], 1);
        }
    }
    __syncthreads();
    for (int i = threadIdx.x; i < NR; i += 256) {   // reserve capacity-based slots
        int c = h[i];
        basev[i] = c ? (i * CAP + atomicAdd(&ccur[i], c)) : 0;
    }
    __syncthreads();
#pragma unroll
    for (int k = 0; k < 4; ++k) {
        if (valid[k]) {
            int d, s, r, p;
#define EMIT(DD, SS, RK) d = (DD); s = (SS); r = d >> 9; \
            p = basev[r] + (RK); \
            cbucket[p] = (unsigned int)(((d & 511) << 17) | s);
            EMIT(dv[k].x, sv[k].x, rank[k][0])
            EMIT(dv[k].y, sv[k].y, rank[k][1])
            EMIT(dv[k].z, sv[k].z, rank[k][2])
            EMIT(dv[k].w, sv[k].w, rank[k][3])
#undef EMIT
        }
    }
}

// ---- C2: per-range local sort, 2 blocks/range (each writes one 256-node half) ----
__global__ __launch_bounds__(512) void k_rangesort(const int* __restrict__ ccur,
                                                   const unsigned int* __restrict__ cbucket,
                                                   int* __restrict__ row_ptr,
                                                   int* __restrict__ bucket,
                                                   float* __restrict__ dinv) {
    __shared__ int part[256];    // range-count prefix (all blocks recompute: cheap)
    __shared__ int h[RSZ];
    __shared__ int lptr[RSZ];
    int r = blockIdx.x >> 1;
    int half = blockIdx.x & 1;
    int t = threadIdx.x;
    if (t < 256) part[t] = (t < NR) ? ccur[t] : 0;
    h[t] = 0;
    __syncthreads();
    for (int off = 1; off < 256; off <<= 1) {       // inclusive scan over 256
        int v = (t >= off && t < 256) ? part[t - off] : 0;
        __syncthreads();
        if (t < 256) part[t] += v;
        __syncthreads();
    }
    int cnt = ccur[r];
    int obeg = part[r] - cnt;                       // compact output base
    int ibeg = r * CAP;                             // capacity input base
    for (int i = t; i < cnt; i += RSZ)              // full-range histogram (both halves)
        atomicAdd(&h[cbucket[ibeg + i] >> 17], 1);
    __syncthreads();
    lptr[t] = h[t];
    __syncthreads();
    for (int off = 1; off < RSZ; off <<= 1) {       // inclusive scan over 512
        int v = (t >= off) ? lptr[t - off] : 0;
        __syncthreads();
        lptr[t] += v;
        __syncthreads();
    }
    int node0 = r * RSZ;
    int v = node0 + t;
    if ((t >> 8) == half && v < NN) {               // own half's nodes only
        int ex = lptr[t] - h[t];                    // exclusive
        row_ptr[v] = obeg + ex;
        dinv[v] = rsqrtf((float)(h[t] + 1));        // +1 self-loop
    }
    __syncthreads();
    h[t] = lptr[t] - h[t];                          // reuse h as LDS cursor
    __syncthreads();
    for (int i = t; i < cnt; i += RSZ) {
        unsigned int w = cbucket[ibeg + i];
        int key = w >> 17;
        if ((key >> 8) == half) {                   // own half's edges only
            int off_ = atomicAdd(&h[key], 1);
            bucket[obeg + off_] = (int)(w & 0x1FFFF);
        }
    }
    if (blockIdx.x == 0 && t == 0) row_ptr[NN] = NE;
}

// ---------------- hs(fp16) = (x @ W1) * dinv[row] ----------------
__global__ __launch_bounds__(256) void k_gemm(const float* __restrict__ x,
                                              const float* __restrict__ W1,
                                              const float* __restrict__ dinv,
                                              __half* __restrict__ hs) {
    __shared__ float sW[NF][NH];        // 16 KB
    __shared__ float sX[32][NF + 4];    // padded: no bank conflict
    int t = threadIdx.x;
    const float4* W4 = (const float4*)W1;
    float4* sW4 = (float4*)&sW[0][0];
#pragma unroll
    for (int i = 0; i < 4; ++i) sW4[t + 256 * i] = W4[t + 256 * i];

    long row0 = (long)blockIdx.x * 32;
    const float* xb = x + row0 * NF;
#pragma unroll
    for (int i = 0; i < 4; ++i) {
        int idx4 = t + 256 * i;
        int r = idx4 >> 5;
        int c = (idx4 & 31) * 4;
        v4f v = __builtin_nontemporal_load((const v4f*)(xb + idx4 * 4));  // single-use stream
        sX[r][c] = v.x; sX[r][c + 1] = v.y; sX[r][c + 2] = v.z; sX[r][c + 3] = v.w;
    }
    __syncthreads();

    int r = t >> 3;
    int c = (t & 7) * 4;
    float4 acc = {0.f, 0.f, 0.f, 0.f};
#pragma unroll 8
    for (int k = 0; k < NF; ++k) {
        float xv = sX[r][k];
        float4 w = *(const float4*)&sW[k][c];
        acc.x += xv * w.x; acc.y += xv * w.y;
        acc.z += xv * w.z; acc.w += xv * w.w;
    }
    float dv = dinv[row0 + r];
    __half2 h01 = __floats2half2_rn(acc.x * dv, acc.y * dv);
    __half2 h23 = __floats2half2_rn(acc.z * dv, acc.w * dv);
    uint2 packed = { *(unsigned int*)&h01, *(unsigned int*)&h23 };
    *(uint2*)&hs[(row0 + r) * NH + c] = packed;   // 8B store, aligned
}

// ---- gather: fp16 packed accumulate, bucket-prefetch, no barrier ----
// First 65 blocks also zero the s|mx|cnt region (aliases dead cbucket tail;
// consumed only by k_pool which runs in a later dispatch).
__global__ __launch_bounds__(256) void k_gath(
    const int* __restrict__ row_ptr, const int* __restrict__ bucket,
    const __half* __restrict__ hs, const float* __restrict__ dinv,
    const float* __restrict__ b1, __half* __restrict__ nodeout,
    v4i* __restrict__ szero) {
    if (blockIdx.x < (ZV4 + 255) / 256) {
        int idx = blockIdx.x * 256 + threadIdx.x;
        if (idx < ZV4) { v4i z = {0, 0, 0, 0}; szero[idx] = z; }
    }
    int wave = threadIdx.x >> 6;
    int lane = threadIdx.x & 63;
    int fq = lane & 3;        // 16B chunk: halves 8*fq..8*fq+7
    int es = lane >> 2;       // edge slot 0..15
    int v = blockIdx.x * 4 + wave;  // NN % 4 == 0: exact
    int beg = row_ptr[v], end = row_ptr[v + 1];
    int n = end - beg;
    int bk = 0;
    if (lane < n) bk = bucket[beg + lane];          // prefetch up to 64 entries
    float dv = dinv[v];
    uint4 sraw = *(const uint4*)&hs[(size_t)v * NH + fq * 8];  // self row

    int u0 = __shfl(bk, es);
    int u1 = __shfl(bk, es + 16);
    int u2 = __shfl(bk, es + 32);
    uint4 r0 = {0, 0, 0, 0}, r1 = {0, 0, 0, 0}, r2 = {0, 0, 0, 0};
    if (es < n)      r0 = *(const uint4*)&hs[(size_t)u0 * NH + fq * 8];
    if (es + 16 < n) r1 = *(const uint4*)&hs[(size_t)u1 * NH + fq * 8];
    if (es + 32 < n) r2 = *(const uint4*)&hs[(size_t)u2 * NH + fq * 8];

    __half2 zero2 = __floats2half2_rn(0.f, 0.f);
    __half2 a0 = zero2, a1 = zero2, a2 = zero2, a3 = zero2;
#define ACC(RR) { \
    a0 = __hadd2(a0, *(__half2*)&RR.x); \
    a1 = __hadd2(a1, *(__half2*)&RR.y); \
    a2 = __hadd2(a2, *(__half2*)&RR.z); \
    a3 = __hadd2(a3, *(__half2*)&RR.w); }
    ACC(r0) ACC(r1) ACC(r2)            // zeros contribute nothing

    for (int base = 48; base < n; base += 16) {     // rare tail (deg > 48: ~0.3%)
        int idx = base + es;
        int u = (idx < 64) ? __shfl(bk, idx) : ((idx < n) ? bucket[beg + idx] : 0);
        if (idx < n) {
            uint4 rr = *(const uint4*)&hs[(size_t)u * NH + fq * 8];
            ACC(rr)
        }
    }
#undef ACC

#pragma unroll
    for (int m = 4; m < 64; m <<= 1) {  // reduce across es: 4 steps x 4 pk_add
        a0 = __hadd2(a0, shfl_xor_h2(a0, m));
        a1 = __hadd2(a1, shfl_xor_h2(a1, m));
        a2 = __hadd2(a2, shfl_xor_h2(a2, m));
        a3 = __hadd2(a3, shfl_xor_h2(a3, m));
    }
    if (es == 0) {
        float2 g0 = __half22float2(a0);
        float2 g1 = __half22float2(a1);
        float2 g2 = __half22float2(a2);
        float2 g3 = __half22float2(a3);
        float2 f0 = __half22float2(*(__half2*)&sraw.x);
        float2 f1 = __half22float2(*(__half2*)&sraw.y);
        float2 f2 = __half22float2(*(__half2*)&sraw.z);
        float2 f3 = __half22float2(*(__half2*)&sraw.w);
        float4 bb0 = *(const float4*)&b1[fq * 8];
        float4 bb1 = *(const float4*)&b1[fq * 8 + 4];
        __half2 p0 = __floats2half2_rn(fmaxf((g0.x + f0.x) * dv + bb0.x, 0.f),
                                       fmaxf((g0.y + f0.y) * dv + bb0.y, 0.f));
        __half2 p1 = __floats2half2_rn(fmaxf((g1.x + f1.x) * dv + bb0.z, 0.f),
                                       fmaxf((g1.y + f1.y) * dv + bb0.w, 0.f));
        __half2 p2 = __floats2half2_rn(fmaxf((g2.x + f2.x) * dv + bb1.x, 0.f),
                                       fmaxf((g2.y + f2.y) * dv + bb1.y, 0.f));
        __half2 p3 = __floats2half2_rn(fmaxf((g3.x + f3.x) * dv + bb1.z, 0.f),
                                       fmaxf((g3.y + f3.y) * dv + bb1.w, 0.f));
        v4i pk;
        pk.x = *(int*)&p0; pk.y = *(int*)&p1; pk.z = *(int*)&p2; pk.w = *(int*)&p3;
        __builtin_nontemporal_store(pk, (v4i*)(nodeout + (size_t)v * NH + fq * 8));
    }
}

// ---------------- pooling: run-merge over sorted batch ----------------
__global__ __launch_bounds__(256) void k_pool(const __half* __restrict__ nodeout,
                                              const int* __restrict__ batch,
                                              float* __restrict__ s,
                                              unsigned int* __restrict__ mx,
                                              float* __restrict__ cnt) {
    int t = threadIdx.x;
    int f = t & 31;
    int v0 = blockIdx.x * PRSZ + (t >> 5) * 16;
    int curg = -1;
    float rs = 0.f, rm = 0.f, rc = 0.f;
    for (int i = 0; i < 16; ++i) {
        int v = v0 + i;
        if (v >= NN) break;
        int g = batch[v];
        float val = __half2float(nodeout[(size_t)v * NH + f]);
        if (g != curg) {
            if (curg >= 0) {
                atomicAdd(&s[curg * NH + f], rs);
                atomicMax(&mx[curg * NH + f], __float_as_uint(rm));
                if (f == 0) atomicAdd(&cnt[curg], rc);
            }
            curg = g; rs = 0.f; rm = 0.f; rc = 0.f;
        }
        rs += val; rm = fmaxf(rm, val); rc += 1.f;
    }
    if (curg >= 0) {
        atomicAdd(&s[curg * NH + f], rs);
        atomicMax(&mx[curg * NH + f], __float_as_uint(rm));  // post-relu >= 0
        if (f == 0) atomicAdd(&cnt[curg], rc);
    }
}

// ---------------- head: out[g] = [s, s/cnt, mx] @ Wg + bg ----------------
__global__ void k_head(const float* __restrict__ s,
                       const unsigned int* __restrict__ mx,
                       const float* __restrict__ cnt,
                       const float* __restrict__ Wg,
                       const float* __restrict__ bg,
                       float* __restrict__ out) {
    int g = blockIdx.x * blockDim.x + threadIdx.x;
    if (g >= NG) return;
    float inv = 1.0f / fmaxf(cnt[g], 1.0f);
    float accv = bg[0];
#pragma unroll 4
    for (int k = 0; k < NH; ++k) {
        float sv = s[g * NH + k];
        float mv = __uint_as_float(mx[g * NH + k]);
        accv += sv * Wg[k] + sv * inv * Wg[NH + k] + mv * Wg[2 * NH + k];
    }
    out[g] = accv;
}

extern "C" void kernel_launch(void* const* d_in, const int* in_sizes, int n_in,
                              void* d_out, int out_size, void* d_ws, size_t ws_size,
                              hipStream_t stream) {
    const float* x     = (const float*)d_in[0];
    const int*   ei    = (const int*)d_in[1];
    const int*   batch = (const int*)d_in[2];
    const float* W1    = (const float*)d_in[3];
    const float* b1    = (const float*)d_in[4];
    const float* Wg    = (const float*)d_in[5];
    const float* bg    = (const float*)d_in[6];
    float* out = (float*)d_out;

    const int* src = ei;        // edge_index[0]
    const int* dst = ei + NE;   // edge_index[1]

    // workspace layout. cbucket (capacity-strided, 13.65 MB) is dead after
    // rangesort; hs, nodeout, s, mx, cnt all alias into its region.
    // s/mx/cnt are zeroed inside k_gath (stream-ordered after rangesort).
    char* ws = (char*)d_ws;
    int*          ccur    = (int*)(ws + 0);          // NR
    int*          row_ptr = (int*)(ws + 1600);       // NN+1
    float*        dinv    = (float*)(ws + 401616);   // NN
    int*          bucket  = (int*)(ws + 801616);     // NE (compact)
    unsigned int* cbucket = (unsigned int*)(ws + 13601664); // NR*CAP words (64B-aligned)
    __half*       hs      = (__half*)(ws + 13601664);       // NN*NH fp16 (alias, 64B-aligned)
    __half*       nodeout = (__half*)(ws + 20001664);       // NN*NH fp16 (alias, 64B-aligned)
    float*        s       = (float*)(ws + 26401664); // NG*NH (alias)
    unsigned int* mx      = (unsigned int*)(ws + 26467200); // (alias)
    float*        cnt     = (float*)(ws + 26532736); // NG (alias)
    // total = 13601664 + 196*17408*4 = 27,249,536 B (< 27.33 MB proven)

    hipMemsetAsync(ccur, 0, NR * sizeof(int), stream);

    k_cscatter<<<NBE, 256, 0, stream>>>(src, dst, ccur, cbucket);
    k_rangesort<<<2 * NR, RSZ, 0, stream>>>(ccur, cbucket, row_ptr, bucket, dinv);
    k_gemm<<<NN / 32, 256, 0, stream>>>(x, W1, dinv, hs);
    k_gath<<<NN / 4, 256, 0, stream>>>(row_ptr, bucket, hs, dinv, b1, nodeout,
                                       (v4i*)s);
    k_pool<<<PNB, 256, 0, stream>>>(nodeout, batch, s, mx, cnt);
    k_head<<<(NG + 255) / 256, 256, 0, stream>>>(s, mx, cnt, Wg, bg, out);
}